// Round 2
// baseline (169.467 us; speedup 1.0000x reference)
//
#include <hip/hip_runtime.h>

// GeodesicLoss: reference's velocity starts at exactly zero, so
// acc = -einsum(Gamma, v, v) == 0 every step and traj == outputs identically.
// Answer = mean_b ||outputs[b] - targets[b]||_2, B=524288, D=32.
// christoffel_symbols (d_in[2]) is mathematically dead.
//
// R1 analysis: grid-stride runtime-bound loop was latency-bound
// (VALUBusy 6.5%, HBM 14%): 1 dependent load->shfl->sqrt chain per iter.
// Fix: compile-time 4-row unroll per 8-lane group, all 8 float4 loads
// hoisted (128 B MLP/thread), contiguous 128-row slab per block.

static constexpr int B_ROWS        = 524288;   // batch
static constexpr int ROWS_PER_GRP  = 4;        // unrolled rows per 8-lane group
static constexpr int GROUPS_PER_BLK = 32;      // 256 threads / 8 lanes
static constexpr int ROWS_PER_BLK  = ROWS_PER_GRP * GROUPS_PER_BLK;  // 128
static constexpr int NUM_BLOCKS    = B_ROWS / ROWS_PER_BLK;          // 4096

__global__ __launch_bounds__(256) void geodesic_loss_kernel(
    const float4* __restrict__ o4,
    const float4* __restrict__ t4,
    float* __restrict__ out)
{
    const int lane8 = threadIdx.x & 7;          // lane within 8-lane row group
    const int grp   = threadIdx.x >> 3;         // group id within block (0..31)
    const int base  = blockIdx.x * ROWS_PER_BLK;

    // Iteration-major mapping: iter i covers rows [base+32i, base+32i+31],
    // so each wave's 8 groups read 1 KiB contiguous per load instruction.
    float4 o[ROWS_PER_GRP], t[ROWS_PER_GRP];
#pragma unroll
    for (int i = 0; i < ROWS_PER_GRP; ++i) {
        const int row = base + i * GROUPS_PER_BLK + grp;
        const int idx = (row << 3) + lane8;     // 8 float4 per 32-float row
        o[i] = o4[idx];
        t[i] = t4[idx];
    }

    float acc = 0.0f;
#pragma unroll
    for (int i = 0; i < ROWS_PER_GRP; ++i) {
        float dx = o[i].x - t[i].x;
        float dy = o[i].y - t[i].y;
        float dz = o[i].z - t[i].z;
        float dw = o[i].w - t[i].w;
        float s = dx * dx + dy * dy + dz * dz + dw * dw;
        // reduce squared distance across the 8 lanes of this row group
        s += __shfl_xor(s, 1);
        s += __shfl_xor(s, 2);
        s += __shfl_xor(s, 4);
        if (lane8 == 0) acc += sqrtf(s);        // 4 independent chains
    }

    // sum the 8 group-leaders within the 64-lane wave
    acc += __shfl_xor(acc, 8);
    acc += __shfl_xor(acc, 16);
    acc += __shfl_xor(acc, 32);

    __shared__ float sm[4];                     // 4 waves per block
    const int wave = threadIdx.x >> 6;
    const int lane = threadIdx.x & 63;
    if (lane == 0) sm[wave] = acc;
    __syncthreads();
    if (threadIdx.x == 0) {
        float total = sm[0] + sm[1] + sm[2] + sm[3];
        atomicAdd(out, total * (1.0f / (float)B_ROWS));
    }
}

extern "C" void kernel_launch(void* const* d_in, const int* in_sizes, int n_in,
                              void* d_out, int out_size, void* d_ws, size_t ws_size,
                              hipStream_t stream) {
    const float4* outputs = (const float4*)d_in[0];
    const float4* targets = (const float4*)d_in[1];
    // d_in[2] (christoffel_symbols) unused: velocity is identically zero.
    float* out = (float*)d_out;

    // d_out is re-poisoned to 0xAA before every timed launch; zero it.
    hipMemsetAsync(out, 0, sizeof(float), stream);

    geodesic_loss_kernel<<<dim3(NUM_BLOCKS), dim3(256), 0, stream>>>(
        outputs, targets, out);
}

// Round 3
// 145.631 us; speedup vs baseline: 1.1637x; 1.1637x over previous
//
#include <hip/hip_runtime.h>

// GeodesicLoss: reference's velocity starts at exactly zero, so
// acc = -einsum(Gamma, v, v) == 0 every step and traj == outputs identically.
// Answer = mean_b ||outputs[b] - targets[b]||_2, B=524288, D=32.
// christoffel_symbols (d_in[2]) is mathematically dead.
//
// R2 post-mortem: VGPR_Count=24 proved the compiler sank the hoisted loads —
// the per-row 3-deep __shfl_xor (ds_swizzle) chain inside the loop made the
// scheduler pick a minimal-register load->wait->swizzle order. Latency-bound
// at 2 TB/s effective.
// R3 fix: LDS-transpose. 16 independent coalesced float4 loads per thread
// with NO cross-lane ops before first use; per-row reduce goes through a
// pad-9 LDS array (2-way bank aliasing = free); one 6-step wave reduce per
// thread amortized over 8 rows.

static constexpr int B_ROWS       = 524288;
static constexpr int ROWS_PER_BLK = 256;                  // = blockDim.x
static constexpr int NUM_BLOCKS   = B_ROWS / ROWS_PER_BLK; // 2048
static constexpr int PAD          = 9;                    // LDS row stride (floats)

__global__ __launch_bounds__(256) void geodesic_loss_kernel(
    const float4* __restrict__ o4,
    const float4* __restrict__ t4,
    float* __restrict__ out)
{
    __shared__ float part[ROWS_PER_BLK * PAD];            // 9216 B

    const int t    = threadIdx.x;
    const int base = blockIdx.x * (ROWS_PER_BLK * 8);     // float4 index, fits int

    // 16 independent, perfectly coalesced loads (1 KiB/wave/instruction).
    float4 o[8], g[8];
#pragma unroll
    for (int k = 0; k < 8; ++k) o[k] = o4[base + k * 256 + t];
#pragma unroll
    for (int k = 0; k < 8; ++k) g[k] = t4[base + k * 256 + t];

    // Per-float4 squared-diff partials -> LDS (row-major, pad 9).
    const int l8 = t & 7;
#pragma unroll
    for (int k = 0; k < 8; ++k) {
        float dx = o[k].x - g[k].x;
        float dy = o[k].y - g[k].y;
        float dz = o[k].z - g[k].z;
        float dw = o[k].w - g[k].w;
        float p  = dx * dx + dy * dy + dz * dz + dw * dw;
        const int rl = (k * 256 + t) >> 3;                // local row 0..255
        part[rl * PAD + l8] = p;
    }
    __syncthreads();

    // Thread t owns local row t: sum its 8 partials, sqrt.
    float ss = 0.0f;
#pragma unroll
    for (int j = 0; j < 8; ++j) ss += part[t * PAD + j];
    float d = sqrtf(ss);

    // One wave reduce per thread (amortized over 8 rows of work).
    d += __shfl_xor(d, 1);
    d += __shfl_xor(d, 2);
    d += __shfl_xor(d, 4);
    d += __shfl_xor(d, 8);
    d += __shfl_xor(d, 16);
    d += __shfl_xor(d, 32);

    __shared__ float sm[4];
    const int wave = t >> 6;
    const int lane = t & 63;
    if (lane == 0) sm[wave] = d;
    __syncthreads();
    if (t == 0) {
        atomicAdd(out, (sm[0] + sm[1] + sm[2] + sm[3]) * (1.0f / (float)B_ROWS));
    }
}

extern "C" void kernel_launch(void* const* d_in, const int* in_sizes, int n_in,
                              void* d_out, int out_size, void* d_ws, size_t ws_size,
                              hipStream_t stream) {
    const float4* outputs = (const float4*)d_in[0];
    const float4* targets = (const float4*)d_in[1];
    // d_in[2] (christoffel_symbols) unused: velocity is identically zero.
    float* out = (float*)d_out;

    // d_out is re-poisoned to 0xAA before every timed launch; zero it.
    hipMemsetAsync(out, 0, sizeof(float), stream);

    geodesic_loss_kernel<<<dim3(NUM_BLOCKS), dim3(256), 0, stream>>>(
        outputs, targets, out);
}